// Round 3
// baseline (784.948 us; speedup 1.0000x reference)
//
#include <hip/hip_runtime.h>

#define NN 100000
#define KK 32
#define DD 512
#define HH 32

// d_ws layout (float offsets) — total ~13.0 MB, small on purpose
#define WC_OFF   0                      // [512][64] = nonneg(qw)/512 | nonneg(kw)/512, layout [k][c]
#define EGO_OFF  32768                  // [32] nonneg(ego_scale)
#define VT_OFF   32800                  // [32][512] Vt[h][d] = nonneg(v_w[d][h])
#define ATTN_OFF 49408                  // [N][32] sum_attn  (12.8 MB)
// q_emb / k_emb are staged in d_out (N*32 floats each = 25.6 MB of 204.8 MB);
// they are dead before pv_kernel overwrites all of d_out.

__device__ __forceinline__ float nonneg_f(float w) {
    // elu(w)+1 = w+1 (w>0) else exp(w)
    return w > 0.0f ? (w + 1.0f) : expf(w);
}

#define FMA4(A, s, W) do { \
    (A).x = fmaf((s), (W).x, (A).x); \
    (A).y = fmaf((s), (W).y, (A).y); \
    (A).z = fmaf((s), (W).z, (A).z); \
    (A).w = fmaf((s), (W).w, (A).w); } while (0)

// ---------------- K0: weight prep -------------------------------------------
__global__ __launch_bounds__(256) void prep_kernel(
    const float* __restrict__ qw, const float* __restrict__ kw,
    const float* __restrict__ ego, const float* __restrict__ vw,
    float* __restrict__ ws)
{
    int idx = blockIdx.x * 256 + threadIdx.x;
    if (idx < 32768) {
        int k = idx >> 6, c = idx & 63;
        float w = (c < HH) ? qw[c * DD + k] : kw[(c - HH) * DD + k];
        ws[WC_OFF + idx] = nonneg_f(w) * (1.0f / DD);   // fold the /d_in
    } else if (idx < 32800) {
        ws[EGO_OFF + (idx - 32768)] = nonneg_f(ego[idx - 32768]);
    } else if (idx < 32800 + HH * DD) {
        int t = idx - 32800;
        int h = t >> 9, d = t & 511;
        ws[VT_OFF + t] = nonneg_f(vw[d * HH + h]);      // transpose
    }
}

// ---------------- K1: q_emb / k_emb = x @ [qw|kw]^T -------------------------
// 512 threads; 128 rows/tile; weights staged in LDS in two 64 KB k-halves.
// Thread (cg,rg): 4 output cols (cg*4..), 4 rows (rg, rg+32, rg+64, rg+96).
__global__ __launch_bounds__(512) void qk_emb_kernel(
    const float* __restrict__ x, const float* __restrict__ ws,
    float* __restrict__ qe, float* __restrict__ ke)
{
    __shared__ float4 Wc4[4096];                    // 64 KB: [256 k][16 c4]
    const float4* x4 = (const float4*)x;
    const int tid = threadIdx.x;
    const int cg = tid & 15;                        // col group: cols cg*4..cg*4+3
    const int rg = tid >> 4;                        // 0..31
    const int ntiles = (NN + 127) >> 7;             // 782

    for (int t = blockIdx.x; t < ntiles; t += gridDim.x) {
        const int base = t << 7;
        float4 acc[4];
        #pragma unroll
        for (int j = 0; j < 4; ++j) acc[j] = make_float4(0.f, 0.f, 0.f, 0.f);

        #pragma unroll
        for (int kh = 0; kh < 2; ++kh) {
            __syncthreads();                        // protect LDS before restage
            const float4* wsrc = (const float4*)(ws + WC_OFF) + kh * 4096;
            #pragma unroll
            for (int i = 0; i < 8; ++i)
                Wc4[i * 512 + tid] = wsrc[i * 512 + tid];
            __syncthreads();

            for (int k0 = 0; k0 < 256; k0 += 4) {
                float4 w0 = Wc4[(k0 + 0) * 16 + cg];
                float4 w1 = Wc4[(k0 + 1) * 16 + cg];
                float4 w2 = Wc4[(k0 + 2) * 16 + cg];
                float4 w3 = Wc4[(k0 + 3) * 16 + cg];
                #pragma unroll
                for (int j = 0; j < 4; ++j) {
                    const int row = base + rg + 32 * j;
                    float4 xv = make_float4(0.f, 0.f, 0.f, 0.f);
                    if (row < NN) xv = x4[row * 128 + kh * 64 + (k0 >> 2)];
                    FMA4(acc[j], xv.x, w0);
                    FMA4(acc[j], xv.y, w1);
                    FMA4(acc[j], xv.z, w2);
                    FMA4(acc[j], xv.w, w3);
                }
            }
        }

        float4* qe4 = (float4*)qe;
        float4* ke4 = (float4*)ke;
        #pragma unroll
        for (int j = 0; j < 4; ++j) {
            const int row = base + rg + 32 * j;
            if (row < NN) {
                if (cg < 8) qe4[row * 8 + cg] = acc[j];
                else        ke4[row * 8 + (cg - 8)] = acc[j];
            }
        }
    }
}

// ---------------- K2a: gather-sum + score + normalize -----------------------
// One wave per node. Lanes 0..31 / 32..63 each hold one h (duplicated halves).
__global__ __launch_bounds__(256) void attn_kernel(
    const int* __restrict__ src, const float* __restrict__ qe,
    const float* __restrict__ ke, const float* __restrict__ ws,
    float* __restrict__ attn)
{
    const int wid  = threadIdx.x >> 6;
    const int lane = threadIdx.x & 63;
    const int i = blockIdx.x * 4 + wid;
    if (i >= NN) return;

    const float* ego = ws + EGO_OFF;

    const int h = lane & 31;
    const int half = lane >> 5;
    const int sidx = src[i * KK + h];               // neighbor index h (dup halves)

    float ksum = 0.0f;
    #pragma unroll
    for (int t = 0; t < 16; ++t) {                  // 2 neighbors per iteration
        int j0 = __shfl(sidx, 2 * t);
        int j1 = __shfl(sidx, 2 * t + 1);
        int jj = half ? j1 : j0;
        ksum += ke[jj * HH + h];                    // 128 B contiguous per half-wave
    }
    ksum += __shfl_xor(ksum, 32);                   // combine even/odd neighbor halves

    const float q = qe[i * HH + h];
    float s = ego[h] * q * q + q * ksum * (1.0f / KK);

    float ns = s;                                   // norm = sum over h
    ns += __shfl_xor(ns, 1);
    ns += __shfl_xor(ns, 2);
    ns += __shfl_xor(ns, 4);
    ns += __shfl_xor(ns, 8);
    ns += __shfl_xor(ns, 16);

    const float a = s / (ns + 1e-9f);
    if (half == 0) attn[i * HH + h] = a;
}

// ---------------- K2b: out = attn (N x 32) @ Vt (32 x 512) ------------------
// 256 threads; Vt staged in LDS (64 KB); 32 rows/tile; thread: 8 rows x 8 cols.
__global__ __launch_bounds__(256) void pv_kernel(
    const float* __restrict__ ws, float* __restrict__ out)
{
    __shared__ float4 Vt4[4096];                    // [32][128] float4
    const int tid = threadIdx.x;
    const float4* vsrc = (const float4*)(ws + VT_OFF);
    #pragma unroll
    for (int i = 0; i < 16; ++i)
        Vt4[i * 256 + tid] = vsrc[i * 256 + tid];
    __syncthreads();

    const float* attn = ws + ATTN_OFF;
    const int cg = tid & 63;                        // float4-col 0..63 (+64)
    const int rg = tid >> 6;                        // 0..3
    float4* out4 = (float4*)out;
    const int ntiles = NN / 32;                     // 3125 exact

    for (int t = blockIdx.x; t < ntiles; t += gridDim.x) {
        const int base = t * 32;
        float4 acc[8][2];
        #pragma unroll
        for (int j = 0; j < 8; ++j) {
            acc[j][0] = make_float4(0.f, 0.f, 0.f, 0.f);
            acc[j][1] = make_float4(0.f, 0.f, 0.f, 0.f);
        }
        for (int h = 0; h < 32; ++h) {
            float4 v0 = Vt4[h * 128 + cg];
            float4 v1 = Vt4[h * 128 + 64 + cg];
            #pragma unroll
            for (int j = 0; j < 8; ++j) {
                const int row = base + rg + 4 * j;
                const float a = attn[row * HH + h]; // wave-uniform -> L1 broadcast
                FMA4(acc[j][0], a, v0);
                FMA4(acc[j][1], a, v1);
            }
        }
        #pragma unroll
        for (int j = 0; j < 8; ++j) {
            const int row = base + rg + 4 * j;
            out4[row * 128 + cg]      = acc[j][0];
            out4[row * 128 + 64 + cg] = acc[j][1];
        }
    }
}

// ---------------- launch ----------------------------------------------------
extern "C" void kernel_launch(void* const* d_in, const int* in_sizes, int n_in,
                              void* d_out, int out_size, void* d_ws, size_t ws_size,
                              hipStream_t stream)
{
    const int*   adj = (const int*)d_in[0];         // [2][N*K]; row 0 = src
    const float* x   = (const float*)d_in[1];
    const float* qw  = (const float*)d_in[2];
    const float* kw  = (const float*)d_in[3];
    const float* ego = (const float*)d_in[4];
    const float* vw  = (const float*)d_in[5];
    float* out = (float*)d_out;
    float* ws  = (float*)d_ws;

    const int* srcIdx = adj;                        // first N*K entries

    // q_emb / k_emb live in d_out scratch; dead before pv_kernel rewrites out.
    float* qe   = out;                              // [N][32]
    float* ke   = out + NN * HH;                    // [N][32]
    float* attn = ws + ATTN_OFF;                    // [N][32]

    prep_kernel<<<193, 256, 0, stream>>>(qw, kw, ego, vw, ws);
    qk_emb_kernel<<<391, 512, 0, stream>>>(x, ws, qe, ke);
    attn_kernel<<<(NN + 3) / 4, 256, 0, stream>>>(srcIdx, qe, ke, ws, attn);
    pv_kernel<<<3125, 256, 0, stream>>>(ws, out);
}

// Round 4
// 474.284 us; speedup vs baseline: 1.6550x; 1.6550x over previous
//
#include <hip/hip_runtime.h>

#define NN 100000
#define KK 32
#define DD 512
#define HH 32

// d_ws layout (float offsets)
#define WC_OFF   0                      // [512][64] = nonneg(qw)/512 | nonneg(kw)/512, [k][c]
#define EGO_OFF  32768                  // [32]
#define VT_OFF   32800                  // [32][512] Vt[h][d] = nonneg(v_w[d][h])
#define ATTN_OFF 49408                  // [N][32] sum_attn (12.8 MB)
// q_emb / k_emb staged in d_out (dead before pv_kernel rewrites all of d_out).

__device__ __forceinline__ float nonneg_f(float w) {
    return w > 0.0f ? (w + 1.0f) : expf(w);   // elu(w)+1
}

#define FMA4(A, s, W) do { \
    (A).x = fmaf((s), (W).x, (A).x); \
    (A).y = fmaf((s), (W).y, (A).y); \
    (A).z = fmaf((s), (W).z, (A).z); \
    (A).w = fmaf((s), (W).w, (A).w); } while (0)

// ---------------- K0: weight prep -------------------------------------------
__global__ __launch_bounds__(256) void prep_kernel(
    const float* __restrict__ qw, const float* __restrict__ kw,
    const float* __restrict__ ego, const float* __restrict__ vw,
    float* __restrict__ ws)
{
    int idx = blockIdx.x * 256 + threadIdx.x;
    if (idx < 32768) {
        int k = idx >> 6, c = idx & 63;
        float w = (c < HH) ? qw[c * DD + k] : kw[(c - HH) * DD + k];
        ws[WC_OFF + idx] = nonneg_f(w) * (1.0f / DD);
    } else if (idx < 32800) {
        ws[EGO_OFF + (idx - 32768)] = nonneg_f(ego[idx - 32768]);
    } else if (idx < 32800 + HH * DD) {
        int t = idx - 32800;
        int h = t >> 9, d = t & 511;
        ws[VT_OFF + t] = nonneg_f(vw[d * HH + h]);
    }
}

// ---------------- K1: q_emb / k_emb = x @ [qw|kw]^T -------------------------
// 256 threads, tile = 128 rows x 64 cols, x-tile + W-chunk staged in LDS,
// register prefetch of next k-chunk. Thread: 4 rows (rg) x 8 cols (cg).
#define BKC 32
#define XSTR 33                                     // padded row stride (floats)
__global__ __launch_bounds__(256) void qk_emb_kernel(
    const float* __restrict__ x, const float* __restrict__ ws,
    float* __restrict__ qe, float* __restrict__ ke)
{
    __shared__ float Xs[128 * XSTR];                // 16.5 KB
    __shared__ float Wsh[BKC * 64];                 // 8 KB
    const float4* x4  = (const float4*)x;
    const float4* wc4 = (const float4*)(ws + WC_OFF);
    float4* Wsh4 = (float4*)Wsh;

    const int tid = threadIdx.x;
    const int cg = tid & 7;                         // cols cg*8 .. cg*8+7
    const int rg = tid >> 3;                        // rows rg*4 .. rg*4+3
    const int sc = tid & 7;                         // staging k-chunk (float4)
    const int sr = tid >> 3;                        // staging row base (+32j)
    const int base = blockIdx.x << 7;               // 782 blocks, 1 tile each

    float4 gx[4], gw[2];

    // load chunk 0 into regs
    {
        #pragma unroll
        for (int j = 0; j < 4; ++j) {
            const int row = base + sr + 32 * j;
            gx[j] = (row < NN) ? x4[row * 128 + sc] : make_float4(0.f,0.f,0.f,0.f);
        }
        gw[0] = wc4[tid];
        gw[1] = wc4[tid + 256];
    }
    // write chunk 0 to LDS
    #pragma unroll
    for (int j = 0; j < 4; ++j) {
        float* dst = &Xs[(sr + 32 * j) * XSTR + sc * 4];
        dst[0] = gx[j].x; dst[1] = gx[j].y; dst[2] = gx[j].z; dst[3] = gx[j].w;
    }
    Wsh4[tid] = gw[0];
    Wsh4[tid + 256] = gw[1];
    __syncthreads();

    float4 acc[4][2];
    #pragma unroll
    for (int i = 0; i < 4; ++i) {
        acc[i][0] = make_float4(0.f,0.f,0.f,0.f);
        acc[i][1] = make_float4(0.f,0.f,0.f,0.f);
    }

    for (int c = 0; c < DD / BKC; ++c) {
        // prefetch chunk c+1 into registers (latency hides under compute)
        if (c < DD / BKC - 1) {
            const int k4 = (c + 1) * (BKC / 4);
            #pragma unroll
            for (int j = 0; j < 4; ++j) {
                const int row = base + sr + 32 * j;
                gx[j] = (row < NN) ? x4[row * 128 + k4 + sc]
                                   : make_float4(0.f,0.f,0.f,0.f);
            }
            gw[0] = wc4[(c + 1) * (BKC * 16) + tid];
            gw[1] = wc4[(c + 1) * (BKC * 16) + tid + 256];
        }

        // compute on chunk c
        #pragma unroll 8
        for (int kl = 0; kl < BKC; ++kl) {
            float4 w0 = Wsh4[kl * 16 + cg * 2];
            float4 w1 = Wsh4[kl * 16 + cg * 2 + 1];
            float xr0 = Xs[(rg * 4 + 0) * XSTR + kl];
            float xr1 = Xs[(rg * 4 + 1) * XSTR + kl];
            float xr2 = Xs[(rg * 4 + 2) * XSTR + kl];
            float xr3 = Xs[(rg * 4 + 3) * XSTR + kl];
            FMA4(acc[0][0], xr0, w0); FMA4(acc[0][1], xr0, w1);
            FMA4(acc[1][0], xr1, w0); FMA4(acc[1][1], xr1, w1);
            FMA4(acc[2][0], xr2, w0); FMA4(acc[2][1], xr2, w1);
            FMA4(acc[3][0], xr3, w0); FMA4(acc[3][1], xr3, w1);
        }
        __syncthreads();
        if (c < DD / BKC - 1) {
            #pragma unroll
            for (int j = 0; j < 4; ++j) {
                float* dst = &Xs[(sr + 32 * j) * XSTR + sc * 4];
                dst[0] = gx[j].x; dst[1] = gx[j].y; dst[2] = gx[j].z; dst[3] = gx[j].w;
            }
            Wsh4[tid] = gw[0];
            Wsh4[tid + 256] = gw[1];
            __syncthreads();
        }
    }

    float4* qe4 = (float4*)qe;
    float4* ke4 = (float4*)ke;
    #pragma unroll
    for (int i = 0; i < 4; ++i) {
        const int row = base + rg * 4 + i;
        if (row < NN) {
            if (cg < 4) {
                qe4[row * 8 + cg * 2]     = acc[i][0];
                qe4[row * 8 + cg * 2 + 1] = acc[i][1];
            } else {
                ke4[row * 8 + (cg - 4) * 2]     = acc[i][0];
                ke4[row * 8 + (cg - 4) * 2 + 1] = acc[i][1];
            }
        }
    }
}

// ---------------- K2a: gather-sum + score + normalize -----------------------
__global__ __launch_bounds__(256) void attn_kernel(
    const int* __restrict__ src, const float* __restrict__ qe,
    const float* __restrict__ ke, const float* __restrict__ ws,
    float* __restrict__ attn)
{
    const int wid  = threadIdx.x >> 6;
    const int lane = threadIdx.x & 63;
    const int i = blockIdx.x * 4 + wid;
    if (i >= NN) return;

    const float* ego = ws + EGO_OFF;
    const int h = lane & 31;
    const int half = lane >> 5;
    const int sidx = src[i * KK + h];

    float ksum = 0.0f;
    #pragma unroll
    for (int t = 0; t < 16; ++t) {
        int j0 = __shfl(sidx, 2 * t);
        int j1 = __shfl(sidx, 2 * t + 1);
        int jj = half ? j1 : j0;
        ksum += ke[jj * HH + h];
    }
    ksum += __shfl_xor(ksum, 32);

    const float q = qe[i * HH + h];
    float s = ego[h] * q * q + q * ksum * (1.0f / KK);

    float ns = s;
    ns += __shfl_xor(ns, 1);
    ns += __shfl_xor(ns, 2);
    ns += __shfl_xor(ns, 4);
    ns += __shfl_xor(ns, 8);
    ns += __shfl_xor(ns, 16);

    const float a = s / (ns + 1e-9f);
    if (half == 0) attn[i * HH + h] = a;
}

// ---------------- K2b: out = attn (N x 32) @ Vt (32 x 512) ------------------
// grid 512 (2 blocks/CU), Vt staged ONCE per block; grid-stride over tiles.
// Wave w handles rows base+w, +4, ... (+28); attn via wave-uniform float4
// global loads (L1-hot). Thread: 8 rows x 8 cols.
__global__ __launch_bounds__(256) void pv_kernel(
    const float* __restrict__ ws, const float* __restrict__ attn,
    float* __restrict__ out)
{
    __shared__ float4 Vt4[4096];                    // 64 KB
    const int tid = threadIdx.x;
    const float4* vsrc = (const float4*)(ws + VT_OFF);
    #pragma unroll
    for (int i = 0; i < 16; ++i)
        Vt4[i * 256 + tid] = vsrc[i * 256 + tid];
    __syncthreads();

    const float4* attn4 = (const float4*)attn;
    const int cg = tid & 63;                        // float4-col 0..63 (+64)
    const int wv = tid >> 6;                        // wave id = row offset
    float4* out4 = (float4*)out;
    const int ntiles = NN / 32;                     // 3125

    for (int t = blockIdx.x; t < ntiles; t += gridDim.x) {
        const int base = t * 32;
        float4 acc[8][2];
        #pragma unroll
        for (int j = 0; j < 8; ++j) {
            acc[j][0] = make_float4(0.f,0.f,0.f,0.f);
            acc[j][1] = make_float4(0.f,0.f,0.f,0.f);
        }
        for (int hq = 0; hq < 8; ++hq) {            // 4 h per block
            float4 aq[8];
            #pragma unroll
            for (int j = 0; j < 8; ++j)             // wave-uniform 16B loads
                aq[j] = attn4[(base + wv + 4 * j) * 8 + hq];
            #pragma unroll
            for (int s = 0; s < 4; ++s) {
                const int h = hq * 4 + s;
                float4 v0 = Vt4[h * 128 + cg];
                float4 v1 = Vt4[h * 128 + 64 + cg];
                #pragma unroll
                for (int j = 0; j < 8; ++j) {
                    const float a = s == 0 ? aq[j].x : s == 1 ? aq[j].y
                                  : s == 2 ? aq[j].z : aq[j].w;
                    FMA4(acc[j][0], a, v0);
                    FMA4(acc[j][1], a, v1);
                }
            }
        }
        #pragma unroll
        for (int j = 0; j < 8; ++j) {
            const int row = base + wv + 4 * j;
            out4[row * 128 + cg]      = acc[j][0];
            out4[row * 128 + 64 + cg] = acc[j][1];
        }
    }
}

// ---------------- launch ----------------------------------------------------
extern "C" void kernel_launch(void* const* d_in, const int* in_sizes, int n_in,
                              void* d_out, int out_size, void* d_ws, size_t ws_size,
                              hipStream_t stream)
{
    const int*   adj = (const int*)d_in[0];
    const float* x   = (const float*)d_in[1];
    const float* qw  = (const float*)d_in[2];
    const float* kw  = (const float*)d_in[3];
    const float* ego = (const float*)d_in[4];
    const float* vw  = (const float*)d_in[5];
    float* out = (float*)d_out;
    float* ws  = (float*)d_ws;

    const int* srcIdx = adj;
    float* qe   = out;                              // d_out scratch
    float* ke   = out + NN * HH;
    float* attn = ws + ATTN_OFF;

    prep_kernel<<<193, 256, 0, stream>>>(qw, kw, ego, vw, ws);
    qk_emb_kernel<<<782, 256, 0, stream>>>(x, ws, qe, ke);
    attn_kernel<<<(NN + 3) / 4, 256, 0, stream>>>(srcIdx, qe, ke, ws, attn);
    pv_kernel<<<512, 256, 0, stream>>>(ws, attn, out);
}

// Round 5
// 442.738 us; speedup vs baseline: 1.7729x; 1.0713x over previous
//
#include <hip/hip_runtime.h>

#define NN 100000
#define KK 32
#define DD 512
#define HH 32

// d_ws layout (float offsets) — ~13.0 MB total
#define WF_OFF   0        // [64 kb][64 n][8] bf16 fragment-ready weights (32768 bf16 = 16384 floats)
#define EGO_OFF  16384    // [32] fp32
#define VT_OFF   16416    // [32][512] fp32 Vt[h][d] = nonneg(v_w[d][h])
#define ATTN_OFF 32800    // [N][32] fp32 sum_attn (12.8 MB)
// d_out scratch: qe fp32 [N][32] at out[0..3.2M); keb bf16 [N][32] at out+3.2M.
// Both dead before pv_kernel rewrites all of d_out.

typedef __bf16 bf16x8 __attribute__((ext_vector_type(8)));
typedef float  f32x4  __attribute__((ext_vector_type(4)));

__device__ __forceinline__ float nonneg_f(float w) {
    return w > 0.0f ? (w + 1.0f) : expf(w);   // elu(w)+1
}

#define FMA4(A, s, W) do { \
    (A).x = fmaf((s), (W).x, (A).x); \
    (A).y = fmaf((s), (W).y, (A).y); \
    (A).z = fmaf((s), (W).z, (A).z); \
    (A).w = fmaf((s), (W).w, (A).w); } while (0)

// ---------------- K0: weight prep -------------------------------------------
// Wf[kb][n][e] = nonneg(W[kb*8+e][n])/512 as bf16, fragment-ready for MFMA B.
__global__ __launch_bounds__(256) void prep_kernel(
    const float* __restrict__ qw, const float* __restrict__ kw,
    const float* __restrict__ ego, const float* __restrict__ vw,
    float* __restrict__ ws)
{
    int idx = blockIdx.x * 256 + threadIdx.x;
    if (idx < 32768) {
        int kb = idx >> 9, n = (idx >> 3) & 63, e = idx & 7;
        int k = kb * 8 + e;
        float w = (n < HH) ? qw[n * DD + k] : kw[(n - HH) * DD + k];
        ((__bf16*)ws)[idx] = (__bf16)(nonneg_f(w) * (1.0f / DD));
    } else if (idx < 32832) {
        int t = idx - 32768;
        if (t < HH) ws[EGO_OFF + t] = nonneg_f(ego[t]);
    } else if (idx < 32832 + HH * DD) {
        int t = idx - 32832;
        int h = t >> 9, d = t & 511;
        ws[VT_OFF + t] = nonneg_f(vw[d * HH + h]);
    }
}

// ---------------- K1: [q_emb|k_emb] = x @ Wc via MFMA bf16 ------------------
// Wave = 32 rows x 64 cols, K=512 in 16 steps of 32. No LDS, no barriers.
// A: x fp32 -> bf16 in flight (each element read once). B: 16B frags from Wf.
__global__ __launch_bounds__(256) void qk_emb_kernel(
    const float* __restrict__ x, const float* __restrict__ ws,
    float* __restrict__ qe, __bf16* __restrict__ keb)
{
    const int tid  = threadIdx.x;
    const int wid  = tid >> 6;
    const int lane = tid & 63;
    const int wt   = blockIdx.x * 4 + wid;          // wave tile 0..3124
    if (wt >= NN / 32) return;

    const int lr = lane & 15;                       // row/col-in-tile
    const int lg = lane >> 4;                       // k-group 0..3
    const int r0 = wt * 32 + lr;                    // row-tile 0 row
    const float4* xa0 = (const float4*)x + r0 * 128 + lg * 2;
    const float4* xa1 = xa0 + 16 * 128;             // row-tile 1 (+16 rows)
    const bf16x8* wf8 = (const bf16x8*)(ws + WF_OFF);

    f32x4 acc[2][4];
    #pragma unroll
    for (int r = 0; r < 2; ++r)
        #pragma unroll
        for (int n = 0; n < 4; ++n)
            acc[r][n] = (f32x4){0.f, 0.f, 0.f, 0.f};

    #pragma unroll 4
    for (int s = 0; s < 16; ++s) {
        float4 a0 = xa0[s * 8], a0b = xa0[s * 8 + 1];
        float4 a1 = xa1[s * 8], a1b = xa1[s * 8 + 1];
        bf16x8 af0, af1;
        af0[0]=(__bf16)a0.x;  af0[1]=(__bf16)a0.y;  af0[2]=(__bf16)a0.z;  af0[3]=(__bf16)a0.w;
        af0[4]=(__bf16)a0b.x; af0[5]=(__bf16)a0b.y; af0[6]=(__bf16)a0b.z; af0[7]=(__bf16)a0b.w;
        af1[0]=(__bf16)a1.x;  af1[1]=(__bf16)a1.y;  af1[2]=(__bf16)a1.z;  af1[3]=(__bf16)a1.w;
        af1[4]=(__bf16)a1b.x; af1[5]=(__bf16)a1b.y; af1[6]=(__bf16)a1b.z; af1[7]=(__bf16)a1b.w;

        const int kb = s * 4 + lg;                  // k-block of 8
        bf16x8 b0 = wf8[kb * 64 +  0 + lr];
        bf16x8 b1 = wf8[kb * 64 + 16 + lr];
        bf16x8 b2 = wf8[kb * 64 + 32 + lr];
        bf16x8 b3 = wf8[kb * 64 + 48 + lr];

        acc[0][0] = __builtin_amdgcn_mfma_f32_16x16x32_bf16(af0, b0, acc[0][0], 0, 0, 0);
        acc[0][1] = __builtin_amdgcn_mfma_f32_16x16x32_bf16(af0, b1, acc[0][1], 0, 0, 0);
        acc[0][2] = __builtin_amdgcn_mfma_f32_16x16x32_bf16(af0, b2, acc[0][2], 0, 0, 0);
        acc[0][3] = __builtin_amdgcn_mfma_f32_16x16x32_bf16(af0, b3, acc[0][3], 0, 0, 0);
        acc[1][0] = __builtin_amdgcn_mfma_f32_16x16x32_bf16(af1, b0, acc[1][0], 0, 0, 0);
        acc[1][1] = __builtin_amdgcn_mfma_f32_16x16x32_bf16(af1, b1, acc[1][1], 0, 0, 0);
        acc[1][2] = __builtin_amdgcn_mfma_f32_16x16x32_bf16(af1, b2, acc[1][2], 0, 0, 0);
        acc[1][3] = __builtin_amdgcn_mfma_f32_16x16x32_bf16(af1, b3, acc[1][3], 0, 0, 0);
    }

    // C/D layout: row=(lane>>4)*4+reg, col=lane&15 (verified m89/m91)
    #pragma unroll
    for (int r = 0; r < 2; ++r) {
        const int gbase = wt * 32 + r * 16 + lg * 4;
        #pragma unroll
        for (int j = 0; j < 4; ++j) {
            const int grow = gbase + j;
            qe[grow * HH + lr]       = acc[r][0][j];
            qe[grow * HH + 16 + lr]  = acc[r][1][j];
            keb[grow * HH + lr]      = (__bf16)acc[r][2][j];
            keb[grow * HH + 16 + lr] = (__bf16)acc[r][3][j];
        }
    }
}

// ---------------- K2a: gather-sum + score + normalize -----------------------
// One wave per node; halves duplicate over neighbor pairs; ke is bf16.
__global__ __launch_bounds__(256) void attn_kernel(
    const int* __restrict__ src, const float* __restrict__ qe,
    const __bf16* __restrict__ keb, const float* __restrict__ ws,
    float* __restrict__ attn)
{
    const int wid  = threadIdx.x >> 6;
    const int lane = threadIdx.x & 63;
    const int i = blockIdx.x * 4 + wid;
    if (i >= NN) return;

    const float* ego = ws + EGO_OFF;
    const int h = lane & 31;
    const int half = lane >> 5;
    const int sidx = src[i * KK + h];

    float ksum = 0.0f;
    #pragma unroll
    for (int t = 0; t < 16; ++t) {
        int j0 = __shfl(sidx, 2 * t);
        int j1 = __shfl(sidx, 2 * t + 1);
        int jj = half ? j1 : j0;
        ksum += (float)keb[jj * HH + h];            // 64 B contiguous per half-wave
    }
    ksum += __shfl_xor(ksum, 32);

    const float q = qe[i * HH + h];
    float s = ego[h] * q * q + q * ksum * (1.0f / KK);

    float ns = s;
    ns += __shfl_xor(ns, 1);
    ns += __shfl_xor(ns, 2);
    ns += __shfl_xor(ns, 4);
    ns += __shfl_xor(ns, 8);
    ns += __shfl_xor(ns, 16);

    const float a = s / (ns + 1e-9f);
    if (half == 0) attn[i * HH + h] = a;
}

// ---------------- K2b: out = attn (N x 32) @ Vt (32 x 512) ------------------
// grid 512 (2 blocks/CU), Vt staged ONCE per block; grid-stride over tiles.
__global__ __launch_bounds__(256) void pv_kernel(
    const float* __restrict__ ws, const float* __restrict__ attn,
    float* __restrict__ out)
{
    __shared__ float4 Vt4[4096];                    // 64 KB
    const int tid = threadIdx.x;
    const float4* vsrc = (const float4*)(ws + VT_OFF);
    #pragma unroll
    for (int i = 0; i < 16; ++i)
        Vt4[i * 256 + tid] = vsrc[i * 256 + tid];
    __syncthreads();

    const float4* attn4 = (const float4*)attn;
    const int cg = tid & 63;
    const int wv = tid >> 6;
    float4* out4 = (float4*)out;
    const int ntiles = NN / 32;                     // 3125

    for (int t = blockIdx.x; t < ntiles; t += gridDim.x) {
        const int base = t * 32;
        float4 acc[8][2];
        #pragma unroll
        for (int j = 0; j < 8; ++j) {
            acc[j][0] = make_float4(0.f,0.f,0.f,0.f);
            acc[j][1] = make_float4(0.f,0.f,0.f,0.f);
        }
        for (int hq = 0; hq < 8; ++hq) {
            float4 aq[8];
            #pragma unroll
            for (int j = 0; j < 8; ++j)
                aq[j] = attn4[(base + wv + 4 * j) * 8 + hq];
            #pragma unroll
            for (int s = 0; s < 4; ++s) {
                const int h = hq * 4 + s;
                float4 v0 = Vt4[h * 128 + cg];
                float4 v1 = Vt4[h * 128 + 64 + cg];
                #pragma unroll
                for (int j = 0; j < 8; ++j) {
                    const float a = s == 0 ? aq[j].x : s == 1 ? aq[j].y
                                  : s == 2 ? aq[j].z : aq[j].w;
                    FMA4(acc[j][0], a, v0);
                    FMA4(acc[j][1], a, v1);
                }
            }
        }
        #pragma unroll
        for (int j = 0; j < 8; ++j) {
            const int row = base + wv + 4 * j;
            out4[row * 128 + cg]      = acc[j][0];
            out4[row * 128 + 64 + cg] = acc[j][1];
        }
    }
}

// ---------------- launch ----------------------------------------------------
extern "C" void kernel_launch(void* const* d_in, const int* in_sizes, int n_in,
                              void* d_out, int out_size, void* d_ws, size_t ws_size,
                              hipStream_t stream)
{
    const int*   adj = (const int*)d_in[0];
    const float* x   = (const float*)d_in[1];
    const float* qw  = (const float*)d_in[2];
    const float* kw  = (const float*)d_in[3];
    const float* ego = (const float*)d_in[4];
    const float* vw  = (const float*)d_in[5];
    float* out = (float*)d_out;
    float* ws  = (float*)d_ws;

    const int* srcIdx = adj;
    float*  qe   = out;                             // d_out scratch [N][32] fp32
    __bf16* keb  = (__bf16*)(out + NN * HH);        // d_out scratch [N][32] bf16
    float*  attn = ws + ATTN_OFF;

    prep_kernel<<<193, 256, 0, stream>>>(qw, kw, ego, vw, ws);
    qk_emb_kernel<<<782, 256, 0, stream>>>(x, ws, qe, keb);
    attn_kernel<<<(NN + 3) / 4, 256, 0, stream>>>(srcIdx, qe, keb, ws, attn);
    pv_kernel<<<512, 256, 0, stream>>>(ws, attn, out);
}